// Round 5
// baseline (401.577 us; speedup 1.0000x reference)
//
#include <hip/hip_runtime.h>
#include <hip/hip_bf16.h>

// Problem constants
#define N_NODES 4096
#define BATCH   128
#define DD      32           // D_IN == D_OUT

typedef float  f32x4  __attribute__((ext_vector_type(4)));
typedef __bf16 bf16x8 __attribute__((ext_vector_type(8)));
typedef __bf16 bf16x4 __attribute__((ext_vector_type(4)));
typedef int    i32x2  __attribute__((ext_vector_type(2)));
typedef int    i32x8  __attribute__((ext_vector_type(8)));

#define PREP_BLOCKS 2048
#define TR_BLOCKS   4096   // 64x64 tiles

// async global->LDS, 16 B per lane. LDS dest must be linear in lane (uniform base + lane*16).
__device__ __forceinline__ void async_copy16(const void* g, void* l) {
    __builtin_amdgcn_global_load_lds(
        (const __attribute__((address_space(1))) unsigned int*)g,
        (__attribute__((address_space(3))) unsigned int*)l,
        16, 0, 0);
}

// pack 4 floats -> 4 fp8 e4m3 bytes (OCP), one dword
__device__ __forceinline__ unsigned pack_fp8x4(float a, float b, float c, float d) {
    int v = __builtin_amdgcn_cvt_pk_fp8_f32(a, b, 0, false);   // bytes 0,1
    v     = __builtin_amdgcn_cvt_pk_fp8_f32(c, d, v, true);    // bytes 2,3
    return (unsigned)v;
}

// ---------------------------------------------------------------------------
// Fused pre-stage. Blocks [0, PREP_BLOCKS): per 16-row tile of x3 [524288 x 32]:
//   T8[m=(b*32+q)][i] = fp8 ( x @ Wn )   (A operand for the fp8 GEMM)
//   Ub[b][i][q]       = bf16( x @ Ws )   (self part, pre-relu, workspace)
// Blocks [PREP_BLOCKS, +TR_BLOCKS): adjT8[j][i] = fp8( adj[i][j] * 4096 )
//   (2^12 scale removed exactly by the GEMM's B e8m0 scale byte 0x73)
// ---------------------------------------------------------------------------
__global__ __launch_bounds__(256) void k_pre(
    const float* __restrict__ x, const float* __restrict__ adj,
    const float* __restrict__ Wn, const float* __restrict__ Ws,
    unsigned char* __restrict__ T8, unsigned char* __restrict__ adjT8,
    __bf16* __restrict__ Ub)
{
    __shared__ float ts[64][65];
    const int tid = threadIdx.x;

    if (blockIdx.x < PREP_BLOCKS) {
        // ---- prep branch (MFMA, no LDS) ----
        const int lane = tid & 63;
        const int gw   = (blockIdx.x * 256 + tid) >> 6;  // wave id 0..8191
        const int m    = lane & 15;   // A row / C col index
        const int quad = lane >> 4;   // k-quad

        // B fragments: Bt[n][k] with n=lane&15, k=quad*8+j  ->  W[k*32+n]
        bf16x8 bn[2], bs[2];
#pragma unroll
        for (int h = 0; h < 2; ++h) {
            const int n = m + h * 16;
#pragma unroll
            for (int j = 0; j < 8; ++j) {
                const int k = quad * 8 + j;
                bn[h][j] = (__bf16)Wn[k * 32 + n];
                bs[h][j] = (__bf16)Ws[k * 32 + n];
            }
        }

        for (int t = gw; t < 32768; t += 8192) {       // 16-row tiles, 4 iters/wave
            const int row0 = t << 4;                   // global row = b*4096 + i0
            const int b    = row0 >> 12;
            const int i0   = row0 & 4095;

            const float4* xp = (const float4*)(x + (size_t)(row0 + m) * DD + quad * 8);
            const float4 x0 = xp[0], x1 = xp[1];
            bf16x8 a;
            a[0] = (__bf16)x0.x; a[1] = (__bf16)x0.y; a[2] = (__bf16)x0.z; a[3] = (__bf16)x0.w;
            a[4] = (__bf16)x1.x; a[5] = (__bf16)x1.y; a[6] = (__bf16)x1.z; a[7] = (__bf16)x1.w;

            const f32x4 z = {};
            const f32x4 cT0 = __builtin_amdgcn_mfma_f32_16x16x32_bf16(a, bn[0], z, 0, 0, 0);
            const f32x4 cT1 = __builtin_amdgcn_mfma_f32_16x16x32_bf16(a, bn[1], z, 0, 0, 0);
            const f32x4 cU0 = __builtin_amdgcn_mfma_f32_16x16x32_bf16(a, bs[0], z, 0, 0, 0);
            const f32x4 cU1 = __builtin_amdgcn_mfma_f32_16x16x32_bf16(a, bs[1], z, 0, 0, 0);

            // C/D: col=lane&15, row=quad*4+reg (i-local, 4 consecutive)
            *(unsigned*)&T8[((size_t)(b * 32 + m))      * N_NODES + i0 + quad * 4] =
                pack_fp8x4(cT0[0], cT0[1], cT0[2], cT0[3]);
            *(unsigned*)&T8[((size_t)(b * 32 + m + 16)) * N_NODES + i0 + quad * 4] =
                pack_fp8x4(cT1[0], cT1[1], cT1[2], cT1[3]);

            __bf16* ub = Ub + (size_t)b * (N_NODES * DD) + (size_t)(i0 + quad * 4) * DD;
#pragma unroll
            for (int r = 0; r < 4; ++r) {
                ub[r * DD + m]      = (__bf16)cU0[r];
                ub[r * DD + m + 16] = (__bf16)cU1[r];
            }
        }
    } else {
        // ---- transpose branch: float4 global loads, scalar LDS writes ----
        const int bid = blockIdx.x - PREP_BLOCKS;
        const int i0  = (bid >> 6) << 6;
        const int j0  = (bid & 63) << 6;
        const int cr  = tid >> 4;          // row group 0..15
        const int cc  = (tid & 15) << 2;   // col 0,4,..60
#pragma unroll
        for (int it = 0; it < 4; ++it) {
            const int row = it * 16 + cr;
            const float4 v = *(const float4*)&adj[(size_t)(i0 + row) * N_NODES + j0 + cc];
            ts[row][cc]     = v.x;   // banks (row + cc + e)%32: <=2-way, free
            ts[row][cc + 1] = v.y;
            ts[row][cc + 2] = v.z;
            ts[row][cc + 3] = v.w;
        }
        __syncthreads();
        const int il = (tid & 7) * 8;
        const int jb = tid >> 3;          // 0..31
#pragma unroll
        for (int rr = 0; rr < 2; ++rr) {
            const int jl = jb + rr * 32;
            float v[8];
#pragma unroll
            for (int k = 0; k < 8; ++k) v[k] = ts[il + k][jl] * 4096.0f;
            uint2 p;
            p.x = pack_fp8x4(v[0], v[1], v[2], v[3]);
            p.y = pack_fp8x4(v[4], v[5], v[6], v[7]);
            *(uint2*)&adjT8[(size_t)(j0 + jl) * N_NODES + i0 + il] = p;
        }
    }
}

// ---------------------------------------------------------------------------
// GEMM: C[m][j] = sum_i T[m][i]*adjT[j][i] — 4096^3 MX-fp8, 128x128 tile,
// BK=128B, 4 waves x (4x4) 16x16x128 f8f6f4 MFMA.
// DOUBLE-BUFFERED LDS (one barrier per K-iter; next tile's global_load_lds is
// in flight during the current tile's MFMAs).
// LDS XOR-swizzled at 16B staging granularity; fragment reads are ds_read_b64
// with lane-ROTATED piece order (jp=(j+lq)&3): the (g&1)*8 half-offset gives
// 16 dword-classes -> every 32-lane phase is <=2-way (free). A b128 read only
// has 8 classes -> structural 4-way (the measured +4 cyc/read last round).
//           out[b*131072 + j*32 + q] = relu(Ub + C),  m = b*32+q
// ---------------------------------------------------------------------------
__global__ __launch_bounds__(256) void k_gemm_neigh(
    const unsigned char* __restrict__ A8,   // T8    [4096][4096] fp8
    const unsigned char* __restrict__ B8,   // adjT8 [4096][4096] fp8 (x4096)
    const __bf16* __restrict__ Ub,          // self part, bf16
    float* __restrict__ out)
{
    __shared__ alignas(16) unsigned char As[2][128 * 128];
    __shared__ alignas(16) unsigned char Bs[2][128 * 128];

    const int tid   = threadIdx.x;
    const int lane  = tid & 63;
    const int wave  = tid >> 6;
    const int bm    = blockIdx.y << 7;
    const int bn    = blockIdx.x << 7;
    const int waveM = (wave >> 1) << 6;
    const int waveN = (wave & 1) << 6;
    const int lr    = lane & 15;   // row (A) / col (B) within 16-tile
    const int lq    = lane >> 4;   // k-chunk (32 bytes)
    const int sw    = lr & 7;      // read-side XOR swizzle

    // staging: row r = tid>>3 (+n*32); source 16B chunk swizzled by r&7 so the
    // LDS image at (r, c16) holds global chunk c16 ^ (r&7)
    const int srow = tid >> 3;
    const int scol = ((tid & 7) ^ (srow & 7)) * 16;
    const unsigned char* ga = A8 + (size_t)(bm + srow) * 4096 + scol;
    const unsigned char* gb = B8 + (size_t)(bn + srow) * 4096 + scol;

    auto stage = [&](int k0, int buf) {
        char* la = (char*)&As[buf][0] + tid * 16;
        char* lb = (char*)&Bs[buf][0] + tid * 16;
#pragma unroll
        for (int n = 0; n < 4; ++n) {
            async_copy16(ga + (size_t)(n * 32) * 4096 + k0, la + n * 4096);
            async_copy16(gb + (size_t)(n * 32) * 4096 + k0, lb + n * 4096);
        }
    };

    f32x4 acc[4][4] = {};

    auto compute = [&](int buf) {
        i32x8 af[4], bfr[4];
#pragma unroll
        for (int t = 0; t < 4; ++t) {
            const int ra = (waveM + t * 16 + lr) * 128;
            const int rb = (waveN + t * 16 + lr) * 128;
#pragma unroll
            for (int j = 0; j < 4; ++j) {
                const int jp  = (j + lq) & 3;           // rotated piece order
                const int g   = 4 * lq + jp;            // global 8B-chunk in row
                const int off = (((g >> 1) ^ sw) << 4) + ((g & 1) << 3);
                const i32x2 va = *(const i32x2*)&As[buf][ra + off];
                const i32x2 vb = *(const i32x2*)&Bs[buf][rb + off];
                af[t][2 * jp]      = va[0];
                af[t][2 * jp + 1]  = va[1];
                bfr[t][2 * jp]     = vb[0];
                bfr[t][2 * jp + 1] = vb[1];
            }
        }
#pragma unroll
        for (int tm = 0; tm < 4; ++tm)
#pragma unroll
            for (int tn = 0; tn < 4; ++tn)
                acc[tm][tn] = __builtin_amdgcn_mfma_scale_f32_16x16x128_f8f6f4(
                    af[tm], bfr[tn], acc[tm][tn],
                    0, 0,              // cbsz=fp8(e4m3), blgp=fp8(e4m3)
                    0, 0x7F,           // A scale: 2^0
                    0, 0x73);          // B scale: 2^-12 (undo adj*4096)
    };

    stage(0, 0);
    for (int k0 = 0; k0 < 4096; k0 += 256) {
        __syncthreads();                       // staging of buf0@k0 complete; prev reads done
        if (k0 + 128 < 4096) stage(k0 + 128, 1);
        compute(0);
        __syncthreads();                       // staging of buf1 complete; buf0 reads done
        if (k0 + 256 < 4096) stage(k0 + 256, 0);
        compute(1);
    }

    // epilogue: C/D col=lane&15 (=j), row=quad*4+reg (=m); q=m&31 contiguous
#pragma unroll
    for (int tm = 0; tm < 4; ++tm) {
        const int gm0 = bm + waveM + tm * 16 + lq * 4;
        const int b   = gm0 >> 5;
        const int q0  = gm0 & 31;
#pragma unroll
        for (int tn = 0; tn < 4; ++tn) {
            const int gj = bn + waveN + tn * 16 + lr;
            const size_t base = (size_t)b * (N_NODES * DD) + (size_t)gj * DD + q0;
            const bf16x4 u = *(const bf16x4*)&Ub[base];
            float4 v;
            v.x = fmaxf(acc[tm][tn][0] + (float)u[0], 0.0f);
            v.y = fmaxf(acc[tm][tn][1] + (float)u[1], 0.0f);
            v.z = fmaxf(acc[tm][tn][2] + (float)u[2], 0.0f);
            v.w = fmaxf(acc[tm][tn][3] + (float)u[3], 0.0f);
            *(float4*)&out[base] = v;
        }
    }
}

extern "C" void kernel_launch(void* const* d_in, const int* in_sizes, int n_in,
                              void* d_out, int out_size, void* d_ws, size_t ws_size,
                              hipStream_t stream) {
    const float* x   = (const float*)d_in[0];  // [128, 4096*32]
    const float* adj = (const float*)d_in[1];  // [4096, 4096]
    const float* Wn  = (const float*)d_in[2];  // [32, 32]
    const float* Ws  = (const float*)d_in[3];  // [32, 32]
    float* out = (float*)d_out;                // [128, 4096*32]

    // workspace: T8 fp8 (16 MB) | adjT8 fp8 (16 MB) | Ub bf16 (32 MB)
    unsigned char* T8    = (unsigned char*)d_ws;
    unsigned char* adjT8 = T8 + (size_t)N_NODES * N_NODES;
    __bf16*        Ubf   = (__bf16*)(adjT8 + (size_t)N_NODES * N_NODES);

    hipLaunchKernelGGL(k_pre, dim3(PREP_BLOCKS + TR_BLOCKS), dim3(256), 0, stream,
                       x, adj, Wn, Ws, T8, adjT8, Ubf);
    hipLaunchKernelGGL(k_gemm_neigh, dim3(32, 32), dim3(256), 0, stream,
                       T8, adjT8, Ubf, out);
}